// Round 7
// baseline (1951.029 us; speedup 1.0000x reference)
//
#include <hip/hip_runtime.h>
#include <stdint.h>

#define HIST 336
#define CNTX 168
#define PRED 24
#define HID 128
#define NFEAT 5
#define EMB 50
#define NLAGS 168
#define IN_DIM 218
#define NSAMP 8192
#define G3 384

// workspace layout (float offsets)
#define WS_XS     0         // 336
#define WS_SC     336       // 1
#define WS_TF     340       // 168*50
#define WS_YM     8740      // 24*50
#define WS_KEYS   9940      // 24*4 uint32 (key_n, key_g per step)
#define WS_ENCGI  10036     // 168*384
#define WS_GISH   74548     // 24*384
#define WS_HLAST  83764     // 128
#define WS_WIHT   83892     // 24*384 (W_ih lag cols transposed)

// ---------------- threefry2x32 core (20 rounds) ----------------
__device__ __forceinline__ uint32_t rotl32(uint32_t v, int r){ return (v<<r)|(v>>(32-r)); }

__device__ __forceinline__ void threefry(uint32_t k0, uint32_t k1, uint32_t x0, uint32_t x1,
                                         uint32_t &o0, uint32_t &o1){
  uint32_t ks2 = k0 ^ k1 ^ 0x1BD11BDAu;
  x0 += k0; x1 += k1;
#define TFR(a) { x0 += x1; x1 = rotl32(x1,(a)); x1 ^= x0; }
  TFR(13) TFR(15) TFR(26) TFR(6)
  x0 += k1; x1 += ks2 + 1u;
  TFR(17) TFR(29) TFR(16) TFR(24)
  x0 += ks2; x1 += k0 + 2u;
  TFR(13) TFR(15) TFR(26) TFR(6)
  x0 += k0; x1 += k1 + 3u;
  TFR(17) TFR(29) TFR(16) TFR(24)
  x0 += k1; x1 += ks2 + 4u;
  TFR(13) TFR(15) TFR(26) TFR(6)
  x0 += ks2; x1 += k0 + 5u;
#undef TFR
  o0 = x0; o1 = x1;
}

// ---------------- partitionable (foldlike) JAX PRNG semantics ----------------
__device__ __forceinline__ void tf_split2(uint32_t k0, uint32_t k1,
                                          uint32_t &a0, uint32_t &a1,
                                          uint32_t &b0, uint32_t &b1){
  threefry(k0,k1, 0u,0u, a0,a1);
  threefry(k0,k1, 0u,1u, b0,b1);
}

__device__ __forceinline__ void tf_split3(uint32_t k0, uint32_t k1,
                                          uint32_t &a0, uint32_t &a1,
                                          uint32_t &b0, uint32_t &b1,
                                          uint32_t &c0, uint32_t &c1){
  threefry(k0,k1, 0u,0u, a0,a1);
  threefry(k0,k1, 0u,1u, b0,b1);
  threefry(k0,k1, 0u,2u, c0,c1);
}

__device__ __forceinline__ uint32_t tf_bits1(uint32_t k0, uint32_t k1){
  uint32_t o0,o1; threefry(k0,k1, 0u,0u, o0,o1); return o0 ^ o1;
}

__device__ __forceinline__ uint32_t tf_bits_at(uint32_t k0, uint32_t k1, uint32_t i){
  uint32_t o0,o1; threefry(k0,k1, 0u,i, o0,o1); return o0 ^ o1;
}

__device__ __forceinline__ float bits_to_f01(uint32_t b){
  return __uint_as_float((b>>9) | 0x3f800000u) - 1.0f;
}

// XLA ErfInv32 polynomial
__device__ __forceinline__ float erfinv32(float x){
  float w = -log1pf(-x*x);
  float p;
  if (w < 5.0f){
    w = w - 2.5f;
    p = 2.81022636e-08f;
    p = fmaf(p, w, 3.43273939e-07f);
    p = fmaf(p, w, -3.5233877e-06f);
    p = fmaf(p, w, -4.39150654e-06f);
    p = fmaf(p, w, 0.00021858087f);
    p = fmaf(p, w, -0.00125372503f);
    p = fmaf(p, w, -0.00417768164f);
    p = fmaf(p, w, 0.246640727f);
    p = fmaf(p, w, 1.50140941f);
  } else {
    w = sqrtf(w) - 3.0f;
    p = -0.000200214257f;
    p = fmaf(p, w, 0.000100950558f);
    p = fmaf(p, w, 0.00134934322f);
    p = fmaf(p, w, -0.00367342844f);
    p = fmaf(p, w, 0.00573950773f);
    p = fmaf(p, w, -0.0076224613f);
    p = fmaf(p, w, 0.00943887047f);
    p = fmaf(p, w, 1.00167406f);
    p = fmaf(p, w, 2.83297682f);
  }
  return p*x;
}

__device__ __forceinline__ float normal_from_key(uint32_t k0, uint32_t k1){
  uint32_t b = tf_bits1(k0,k1);
  const float lo = -0.99999994f;
  float f = bits_to_f01(b);
  float u = fmaxf(lo, f*2.0f + lo);
  return 1.41421356f * erfinv32(u);
}

// JAX _gamma_one, alpha >= 1 branch (boost==1)
__device__ float gamma_sample(uint32_t k0, uint32_t k1, float alpha){
  float d = __fsub_rn(alpha, 0.33333334f);
  float c = 0.33333334f / sqrtf(d);
  uint32_t ck0,ck1, sb0,sb1;
  tf_split2(k0,k1, ck0,ck1, sb0,sb1);
  float V;
  for(;;){
    uint32_t nk0,nk1, xk0,xk1, uk0,uk1;
    tf_split3(ck0,ck1, nk0,nk1, xk0,xk1, uk0,uk1);
    ck0=nk0; ck1=nk1;
    float x, v;
    do {
      uint32_t xa0,xa1, xb0,xb1;
      tf_split2(xk0,xk1, xa0,xa1, xb0,xb1);
      xk0=xa0; xk1=xa1;
      x = normal_from_key(xb0,xb1);
      v = __fadd_rn(1.0f, __fmul_rn(x, c));
    } while (v <= 0.0f);
    float X  = __fmul_rn(x, x);
    float Vv = __fmul_rn(__fmul_rn(v, v), v);
    float U  = bits_to_f01(tf_bits1(uk0,uk1));
    float t1 = __fsub_rn(1.0f, __fmul_rn(0.0331f, __fmul_rn(X, X)));
    bool cont = (U >= t1);
    if (cont){
      float lhs = logf(U);
      float rhs = __fadd_rn(__fmul_rn(0.5f, X),
                  __fmul_rn(d, __fadd_rn(__fsub_rn(1.0f, Vv), logf(Vv))));
      cont = (lhs >= rhs);
    }
    if (!cont){ V = Vv; break; }
  }
  return d*V;
}

__device__ __forceinline__ float softplus_f(float x){
  float amax = fmaxf(x, 0.0f);
  return amax + log1pf(expf(-fabsf(x)));
}

// ---------------- K1: scale, xs, tf, ym, step keys ----------------
__global__ __launch_bounds__(256) void k1_prep(const float* __restrict__ x,
                                               const float* __restrict__ xmark,
                                               const float* __restrict__ ymark,
                                               const float* __restrict__ Wemb,
                                               const float* __restrict__ bemb,
                                               float* __restrict__ ws){
  __shared__ float red[256];
  __shared__ float s_sc;
  int t = threadIdx.x;
  float a = 0.f;
  if (t < CNTX) a = fabsf(x[CNTX + t]);
  red[t] = a;
  __syncthreads();
  for(int s=128; s>0; s>>=1){ if(t<s) red[t]+=red[t+s]; __syncthreads(); }
  if (t==0){ s_sc = fmaxf(red[0]/168.0f, 1e-5f); ws[WS_SC]=s_sc; }
  __syncthreads();
  float sc = s_sc;
  for(int i=t; i<HIST; i+=256) ws[WS_XS+i] = x[i]/sc;
  for(int idx=t; idx<CNTX*EMB; idx+=256){
    int tt = idx/EMB, e = idx%EMB;
    float acc = bemb[e];
    for(int f=0; f<NFEAT; f++) acc += xmark[(CNTX+tt)*NFEAT+f]*Wemb[f*EMB+e];
    ws[WS_TF+idx] = acc;
  }
  for(int idx=t; idx<PRED*EMB; idx+=256){
    int kk = idx/EMB, e = idx%EMB;
    float acc = bemb[e];
    for(int f=0; f<NFEAT; f++) acc += ymark[kk*NFEAT+f]*Wemb[f*EMB+e];
    ws[WS_YM+idx] = acc;
  }
  if (t==0){
    uint32_t* kp = reinterpret_cast<uint32_t*>(ws + WS_KEYS);
    uint32_t c0 = 0u, c1 = 42u;
    for(int k=0;k<PRED;k++){
      uint32_t a0,a1,b0,b1;
      tf_split2(c0,c1, a0,a1, b0,b1);
      c0=a0; c1=a1;
      uint32_t n0,n1,g0,g1;
      tf_split2(b0,b1, n0,n1, g0,g1);
      kp[k*4+0]=n0; kp[k*4+1]=n1; kp[k*4+2]=g0; kp[k*4+3]=g1;
    }
  }
}

// ---------------- K2: enc_gi (t<168) and gi_shared (t>=168) ----------------
__global__ __launch_bounds__(256) void k2_gi(const float* __restrict__ Wih,
                                             const float* __restrict__ bih,
                                             const float* __restrict__ bhh,
                                             float* __restrict__ ws){
  int idx = blockIdx.x*256 + threadIdx.x;
  if (idx >= 192*G3) return;
  int t = idx / G3, r = idx % G3;
  const float* wr = Wih + r*IN_DIM;
  const float* xs = ws + WS_XS;
  float acc = bih[r] + (r < 256 ? bhh[r] : 0.0f);
  if (t < CNTX){
    const float* tf = ws + WS_TF + t*EMB;
    for(int j=0;j<NLAGS;j++) acc += wr[j]*xs[CNTX + t - 1 - j];
    for(int e=0;e<EMB;e++)   acc += wr[NLAGS+e]*tf[e];
    ws[WS_ENCGI + t*G3 + r] = acc;
  } else {
    int k = t - CNTX;
    const float* ym = ws + WS_YM + k*EMB;
    for(int e=0;e<EMB;e++)   acc += wr[NLAGS+e]*ym[e];
    for(int i=k;i<NLAGS;i++) acc += wr[i]*xs[HIST-1-i+k];
    ws[WS_GISH + k*G3 + r] = acc;
  }
}

// ---------------- K2b: transpose W_ih lag cols 0..23 ----------------
__global__ __launch_bounds__(256) void k2b_wiht(const float* __restrict__ Wih,
                                                float* __restrict__ ws){
  int idx = blockIdx.x*256 + threadIdx.x;
  if (idx >= PRED*G3) return;
  int r = idx / PRED, i = idx % PRED;
  ws[WS_WIHT + i*G3 + r] = Wih[r*IN_DIM + i];
}

// ---------------- K3: encoder GRU (unchanged from passing r5/r6) ----------------
__global__ __launch_bounds__(384) void k3_enc(const float* __restrict__ Whh,
                                              const float* __restrict__ bhh,
                                              float* __restrict__ ws){
  __shared__ __align__(16) float h[HID];
  __shared__ float grz[256];
  __shared__ float hnv[HID];
  int r = threadIdx.x;
  float4 w[32];
  const float4* wr = (const float4*)(Whh + r*HID);
  #pragma unroll
  for(int i=0;i<32;i++) w[i] = wr[i];
  float bh = (r>=256)? bhh[r] : 0.0f;
  if (r < HID) h[r] = 0.0f;
  __syncthreads();
  const float* encgi = ws + WS_ENCGI;
  for(int t=0;t<CNTX;t++){
    float acc = 0.f;
    #pragma unroll
    for(int i=0;i<32;i++){
      float4 hv = *(const float4*)&h[4*i];
      float4 ww = w[i];
      acc = fmaf(ww.x,hv.x, fmaf(ww.y,hv.y, fmaf(ww.z,hv.z, fmaf(ww.w,hv.w, acc))));
    }
    if (r < 256) grz[r] = encgi[t*G3+r] + acc;
    else         hnv[r-256] = acc + bh;
    __syncthreads();
    if (r < HID){
      float rr = 1.0f/(1.0f+expf(-grz[r]));
      float zz = 1.0f/(1.0f+expf(-grz[128+r]));
      float inv = encgi[t*G3+256+r];
      float nn = tanhf(inv + rr*hnv[r]);
      h[r] = (1.0f-zz)*nn + zz*h[r];
    }
    __syncthreads();
  }
  if (r < HID) ws[WS_HLAST + r] = h[r];
}

// ---------------- K4: decoder — W in registers, h broadcast from LDS ----------------
// 256 blocks x 384 threads (thread = gate-row). 32 samples/block.
// Per (row, sample): acc = gish + lags(seq) + W.h (k ascending 0..127) — bit-identical
// accumulation order to the r5 passing kernel.
#define SPB 32
#define THR4 384

__global__ __launch_bounds__(384, 2) void k4_dec(const float* __restrict__ Whh,
                                                 const float* __restrict__ bhh,
                                                 const float* __restrict__ Wproj,
                                                 const float* __restrict__ bproj,
                                                 const float* __restrict__ ws,
                                                 float* __restrict__ out){
  __shared__ float g[512][33];       // rows 0..383: R/Z/IN accs; 384..511: HN accs (67.6 KB)
  __shared__ float h[SPB][129];      // 16.5 KB, bank-free writes/reads
  __shared__ float wihT_l[24*G3];    // 36.9 KB lag weights
  __shared__ float shist[SPB][25];
  __shared__ float wp[HID*3];
  __shared__ float bp[3];
  __shared__ uint32_t skeys[PRED*4];

  int t = threadIdx.x;
  int b = blockIdx.x;
  int r = t;                          // this thread's gate row

  // W row -> 32 float4 registers (one-time, L2-resident)
  float4 w[32];
  {
    const float4* wr = (const float4*)(Whh + r*HID);
    #pragma unroll
    for(int i=0;i<32;i++) w[i] = wr[i];
  }
  float bhn = (r >= 256) ? bhh[r] : 0.0f;

  for(int idx=t; idx<24*G3; idx+=THR4) wihT_l[idx] = ws[WS_WIHT + idx];
  for(int idx=t; idx<HID*3; idx+=THR4) wp[idx] = Wproj[idx];
  if (t < 3) bp[t] = bproj[t];
  if (t < PRED*4) skeys[t] = reinterpret_cast<const uint32_t*>(ws + WS_KEYS)[t];
  if (t < HID){
    float hl = ws[WS_HLAST + t];
    for(int s=0;s<SPB;s++) h[s][t] = hl;
  }
  float sc = ws[WS_SC];
  const float* gish = ws + WS_GISH;
  __syncthreads();

  #pragma unroll 1
  for(int k=0;k<PRED;k++){
    float gk_init = gish[k*G3 + r];
    // ---- matvec: 8 groups of 4 samples ----
    #pragma unroll 1
    for(int sg=0; sg<8; sg++){
      int s0 = sg*4;
      float a0=gk_init, a1=gk_init, a2=gk_init, a3=gk_init;  // R/Z full acc; n: IN acc
      float c0=bhn, c1=bhn, c2=bhn, c3=bhn;                  // n: HN acc
      // lag part (sequential i, matches r5)
      #pragma unroll 1
      for(int i=0;i<k;i++){
        float wv = wihT_l[i*G3 + r];
        a0 = fmaf(wv, shist[s0+0][k-1-i], a0);
        a1 = fmaf(wv, shist[s0+1][k-1-i], a1);
        a2 = fmaf(wv, shist[s0+2][k-1-i], a2);
        a3 = fmaf(wv, shist[s0+3][k-1-i], a3);
      }
      // main W.h, k ascending (broadcast b128 reads of h)
      if (r < 256){
        #pragma unroll
        for(int q=0;q<32;q++){
          float4 h0 = *(const float4*)&h[s0+0][q*4];
          float4 h1 = *(const float4*)&h[s0+1][q*4];
          float4 h2 = *(const float4*)&h[s0+2][q*4];
          float4 h3 = *(const float4*)&h[s0+3][q*4];
          float4 ww = w[q];
          a0 = fmaf(ww.x,h0.x,a0); a1 = fmaf(ww.x,h1.x,a1); a2 = fmaf(ww.x,h2.x,a2); a3 = fmaf(ww.x,h3.x,a3);
          a0 = fmaf(ww.y,h0.y,a0); a1 = fmaf(ww.y,h1.y,a1); a2 = fmaf(ww.y,h2.y,a2); a3 = fmaf(ww.y,h3.y,a3);
          a0 = fmaf(ww.z,h0.z,a0); a1 = fmaf(ww.z,h1.z,a1); a2 = fmaf(ww.z,h2.z,a2); a3 = fmaf(ww.z,h3.z,a3);
          a0 = fmaf(ww.w,h0.w,a0); a1 = fmaf(ww.w,h1.w,a1); a2 = fmaf(ww.w,h2.w,a2); a3 = fmaf(ww.w,h3.w,a3);
        }
        g[r][s0+0]=a0; g[r][s0+1]=a1; g[r][s0+2]=a2; g[r][s0+3]=a3;
      } else {
        #pragma unroll
        for(int q=0;q<32;q++){
          float4 h0 = *(const float4*)&h[s0+0][q*4];
          float4 h1 = *(const float4*)&h[s0+1][q*4];
          float4 h2 = *(const float4*)&h[s0+2][q*4];
          float4 h3 = *(const float4*)&h[s0+3][q*4];
          float4 ww = w[q];
          c0 = fmaf(ww.x,h0.x,c0); c1 = fmaf(ww.x,h1.x,c1); c2 = fmaf(ww.x,h2.x,c2); c3 = fmaf(ww.x,h3.x,c3);
          c0 = fmaf(ww.y,h0.y,c0); c1 = fmaf(ww.y,h1.y,c1); c2 = fmaf(ww.y,h2.y,c2); c3 = fmaf(ww.y,h3.y,c3);
          c0 = fmaf(ww.z,h0.z,c0); c1 = fmaf(ww.z,h1.z,c1); c2 = fmaf(ww.z,h2.z,c2); c3 = fmaf(ww.z,h3.z,c3);
          c0 = fmaf(ww.w,h0.w,c0); c1 = fmaf(ww.w,h1.w,c1); c2 = fmaf(ww.w,h2.w,c2); c3 = fmaf(ww.w,h3.w,c3);
        }
        g[r][s0+0]=a0; g[r][s0+1]=a1; g[r][s0+2]=a2; g[r][s0+3]=a3;        // IN
        g[r+128][s0+0]=c0; g[r+128][s0+1]=c1; g[r+128][s0+2]=c2; g[r+128][s0+3]=c3; // HN
      }
    }
    __syncthreads();
    // ---- gates + h update (same formulas/order as r5) ----
    {
      int j = t & 127, sgrp = t >> 7;
      for(int s=sgrp; s<SPB; s+=3){
        float aRv = g[j][s], aZv = g[128+j][s], aINv = g[256+j][s], aHNv = g[384+j][s];
        float rr = 1.0f/(1.0f+expf(-aRv));
        float zz = 1.0f/(1.0f+expf(-aZv));
        float nn = tanhf(aINv + rr*aHNv);
        h[s][j] = (1.0f-zz)*nn + zz*h[s][j];
      }
    }
    __syncthreads();
    // ---- projection + sampling: wave 0 lanes 0..31 (identical math/order to r5) ----
    if (t < SPB){
      int s = t, gs = b*SPB + s;
      float p0 = bp[0], p1 = bp[1], p2 = bp[2];
      for(int l=0;l<HID;l++){
        float hv = h[s][l];
        p0 = fmaf(hv, wp[l*3+0], p0);
        p1 = fmaf(hv, wp[l*3+1], p1);
        p2 = fmaf(hv, wp[l*3+2], p2);
      }
      float loc = p1;
      float df = 2.0f + softplus_f(p0);
      float half_df = df*0.5f;
      float sigma = softplus_f(p2);
      uint32_t kn0 = skeys[k*4+0], kn1 = skeys[k*4+1];
      uint32_t kg0 = skeys[k*4+2], kg1 = skeys[k*4+3];
      uint32_t bnb = tf_bits_at(kn0, kn1, (uint32_t)gs);
      const float lo = -0.99999994f;
      float un = fmaxf(lo, bits_to_f01(bnb)*2.0f + lo);
      float nval = 1.41421356f * erfinv32(un);
      uint32_t gk0, gk1;
      threefry(kg0, kg1, 0u, (uint32_t)gs, gk0, gk1);
      float gmm = gamma_sample(gk0, gk1, half_df);
      float tval = nval * sqrtf(half_df / gmm);
      float samp = (loc + sigma*tval)*sc;
      out[gs*PRED + k] = samp;
      shist[s][k] = samp / sc;
    }
    __syncthreads();
  }
}

extern "C" void kernel_launch(void* const* d_in, const int* in_sizes, int n_in,
                              void* d_out, int out_size, void* d_ws, size_t ws_size,
                              hipStream_t stream){
  const float* x     = (const float*)d_in[0];
  const float* xmark = (const float*)d_in[1];
  const float* ymark = (const float*)d_in[2];
  const float* Wemb  = (const float*)d_in[3];
  const float* bemb  = (const float*)d_in[4];
  const float* Wih   = (const float*)d_in[5];
  const float* Whh   = (const float*)d_in[6];
  const float* bih   = (const float*)d_in[7];
  const float* bhh   = (const float*)d_in[8];
  const float* Wproj = (const float*)d_in[9];
  const float* bproj = (const float*)d_in[10];
  float* ws  = (float*)d_ws;
  float* out = (float*)d_out;

  hipLaunchKernelGGL(k1_prep, dim3(1), dim3(256), 0, stream, x, xmark, ymark, Wemb, bemb, ws);
  hipLaunchKernelGGL(k2_gi, dim3(288), dim3(256), 0, stream, Wih, bih, bhh, ws);
  hipLaunchKernelGGL(k2b_wiht, dim3((PRED*G3+255)/256), dim3(256), 0, stream, Wih, ws);
  hipLaunchKernelGGL(k3_enc, dim3(1), dim3(384), 0, stream, Whh, bhh, ws);
  hipLaunchKernelGGL(k4_dec, dim3(NSAMP/SPB), dim3(THR4), 0, stream, Whh, bhh, Wproj, bproj, ws, out);
}